// Round 5
// baseline (11.427 us; speedup 1.0000x reference)
//
#include <hip/hip_runtime.h>

// 4-qubit VQC forward, closed form via Heisenberg-picture Pauli propagation.
// out_w = batch-uniform-coeff dot products of per-wire cos/sin monomials of x.
// NS=2 samples/thread, exact-cover grid -> 32 waves/CU (max occupancy) streaming.

#define NS 2  // samples per thread

__global__ __launch_bounds__(256) void qsim_kernel(const float4* __restrict__ x,
                                                   const float* __restrict__ wt,
                                                   float4* __restrict__ out, int B) {
    int tid = blockIdx.x * blockDim.x + threadIdx.x;
    int S = gridDim.x * blockDim.x;

    // ---- issue all sample loads first (coalesced float4, stride S) ----
    float4 xs[NS];
#pragma unroll
    for (int k = 0; k < NS; ++k) {
        int i = tid + k * S;
        if (i < B) xs[k] = x[i];
    }

    // ---- batch-uniform coefficients (wt[0..3]=layer1 full angles, wt[4..7]=layer2) ----
    float A[4], Bq[4], cF[4], sF[4];
#pragma unroll
    for (int q = 0; q < 4; ++q) {
        A[q]  = __cosf(wt[q]);
        Bq[q] = __sinf(wt[q]);
        cF[q] = __cosf(wt[4 + q]);
        sF[q] = __sinf(wt[4 + q]);
    }
    float C0z =  cF[0] * A[0];
    float C0a = -sF[0] * Bq[0] * Bq[1] * Bq[2] * Bq[3];
    float C0b =  sF[0] * A[0] * Bq[1] * A[2] * Bq[3];
    float C0c =  sF[0] * Bq[0] * A[1] * Bq[2] * A[3];
    float C0d =  sF[0] * Bq[0] * Bq[1] * A[2] * Bq[3];
    float C1z =  cF[1] * A[0] * A[1];
    float C1a = -sF[1] * Bq[1] * Bq[2] * Bq[3];
    float C1b =  sF[1] * Bq[1] * A[2] * Bq[3];
    float C1c =  sF[1] * A[1] * Bq[2] * A[3];
    float C2z =  cF[2] * A[1] * A[2];
    float C2a = -sF[2] * Bq[2] * Bq[3];
    float C2b =  sF[2] * A[2] * Bq[3];
    float C3z =  cF[3] * A[2] * A[3];
    float C3y =  cF[3] * Bq[2] * A[3];
    float C3a = -sF[3] * Bq[3];

#pragma unroll
    for (int k = 0; k < NS; ++k) {
        int i = tid + k * S;
        if (i >= B) continue;
        float4 xv = xs[k];

        float g0 = __cosf(xv.x), h0 = __sinf(xv.x);
        float g1 = __cosf(xv.y), h1 = __sinf(xv.y);
        float g2 = __cosf(xv.z), h2 = __sinf(xv.z);
        float g3 = __cosf(xv.w), h3 = __sinf(xv.w);

        float h23 = h2 * h3, h12 = h1 * h2, h01 = h0 * h1;
        float g03 = g0 * g3, g13 = g1 * g3, g23 = g2 * g3;
        float g02 = g0 * g2, g01 = g0 * g1;

        float4 ov;
        ov.x = C0z * g0 + C0a * g3 + C0b * (h01 * g23) + C0c * (g0 * h12) + C0d * (g1 * h23);
        ov.y = C1z * g1 + C1a * g03 + C1b * (g01 * h23) + C1c * h12;
        ov.z = C2z * g02 + C2a * g13 + C2b * h23;
        ov.w = C3z * g13 + C3y * h23 + C3a * g23;
        out[i] = ov;
    }
}

extern "C" void kernel_launch(void* const* d_in, const int* in_sizes, int n_in,
                              void* d_out, int out_size, void* d_ws, size_t ws_size,
                              hipStream_t stream) {
    const float4* x = (const float4*)d_in[0];   // [B,4]
    const float* w  = (const float*)d_in[1];    // [2,4]
    float4* out = (float4*)d_out;               // [B,4]
    int B = in_sizes[0] / 4;

    int threads = (B + NS - 1) / NS;
    int blocks = (threads + 255) / 256;
    qsim_kernel<<<blocks, 256, 0, stream>>>(x, w, out, B);
}

// Round 7
// 10.478 us; speedup vs baseline: 1.0906x; 1.0906x over previous
//
#include <hip/hip_runtime.h>

// 4-qubit VQC forward, closed form via Heisenberg-picture Pauli propagation.
// out_w = batch-uniform-coeff dot products of per-wire cos/sin monomials of x.
// Streaming micro-opt round: nontemporal (nt) loads/stores for the touch-once
// x/out streams (native clang vector type for the builtin), NS=4, stride-S.

typedef float v4f __attribute__((ext_vector_type(4)));

#define NS 4  // samples per thread

__global__ __launch_bounds__(256) void qsim_kernel(const v4f* __restrict__ x,
                                                   const float* __restrict__ wt,
                                                   v4f* __restrict__ out, int B) {
    int tid = blockIdx.x * blockDim.x + threadIdx.x;
    int S = gridDim.x * blockDim.x;

    // ---- issue all sample loads first (coalesced 16B, stride S, nontemporal) ----
    v4f xs[NS];
#pragma unroll
    for (int k = 0; k < NS; ++k) {
        int i = tid + k * S;
        if (i < B) xs[k] = __builtin_nontemporal_load(&x[i]);
    }

    // ---- batch-uniform coefficients (wt[0..3]=layer1 full angles, wt[4..7]=layer2) ----
    float A[4], Bq[4], cF[4], sF[4];
#pragma unroll
    for (int q = 0; q < 4; ++q) {
        A[q]  = __cosf(wt[q]);
        Bq[q] = __sinf(wt[q]);
        cF[q] = __cosf(wt[4 + q]);
        sF[q] = __sinf(wt[4 + q]);
    }
    float C0z =  cF[0] * A[0];
    float C0a = -sF[0] * Bq[0] * Bq[1] * Bq[2] * Bq[3];
    float C0b =  sF[0] * A[0] * Bq[1] * A[2] * Bq[3];
    float C0c =  sF[0] * Bq[0] * A[1] * Bq[2] * A[3];
    float C0d =  sF[0] * Bq[0] * Bq[1] * A[2] * Bq[3];
    float C1z =  cF[1] * A[0] * A[1];
    float C1a = -sF[1] * Bq[1] * Bq[2] * Bq[3];
    float C1b =  sF[1] * Bq[1] * A[2] * Bq[3];
    float C1c =  sF[1] * A[1] * Bq[2] * A[3];
    float C2z =  cF[2] * A[1] * A[2];
    float C2a = -sF[2] * Bq[2] * Bq[3];
    float C2b =  sF[2] * A[2] * Bq[3];
    float C3z =  cF[3] * A[2] * A[3];
    float C3y =  cF[3] * Bq[2] * A[3];
    float C3a = -sF[3] * Bq[3];

#pragma unroll
    for (int k = 0; k < NS; ++k) {
        int i = tid + k * S;
        if (i >= B) continue;
        v4f xv = xs[k];

        float g0 = __cosf(xv.x), h0 = __sinf(xv.x);
        float g1 = __cosf(xv.y), h1 = __sinf(xv.y);
        float g2 = __cosf(xv.z), h2 = __sinf(xv.z);
        float g3 = __cosf(xv.w), h3 = __sinf(xv.w);

        float h23 = h2 * h3, h12 = h1 * h2, h01 = h0 * h1;
        float g03 = g0 * g3, g13 = g1 * g3, g23 = g2 * g3;
        float g02 = g0 * g2, g01 = g0 * g1;

        v4f ov;
        ov.x = C0z * g0 + C0a * g3 + C0b * (h01 * g23) + C0c * (g0 * h12) + C0d * (g1 * h23);
        ov.y = C1z * g1 + C1a * g03 + C1b * (g01 * h23) + C1c * h12;
        ov.z = C2z * g02 + C2a * g13 + C2b * h23;
        ov.w = C3z * g13 + C3y * h23 + C3a * g23;
        __builtin_nontemporal_store(ov, &out[i]);
    }
}

extern "C" void kernel_launch(void* const* d_in, const int* in_sizes, int n_in,
                              void* d_out, int out_size, void* d_ws, size_t ws_size,
                              hipStream_t stream) {
    const v4f* x = (const v4f*)d_in[0];   // [B,4]
    const float* w = (const float*)d_in[1]; // [2,4]
    v4f* out = (v4f*)d_out;               // [B,4]
    int B = in_sizes[0] / 4;

    int threads = (B + NS - 1) / NS;
    int blocks = (threads + 255) / 256;
    qsim_kernel<<<blocks, 256, 0, stream>>>(x, w, out, B);
}